// Round 1
// baseline (200.483 us; speedup 1.0000x reference)
//
#include <hip/hip_runtime.h>

// SupProtoConLoss on MI355X — round 12: direct-B (barrier-free main loop).
// League: R7 LDS-B 2-barrier = 110.5us; R11 = 115us (LDS pipe ~5x oversub vs
// MFMA + ~800cy/iter barrier/drain tax). R9 direct-B was best per-wave but
// spilled occupancy (VGPR 244 + 64 AGPR > 256 -> 1 block/CU).
// R12 = direct-B with register discipline:
//   - A panel staged once to LDS (64 KB, chunk-major), read as b128 frags.
//   - B fragments loaded straight from L2 (per-lane contiguous 16 B), ping-
//     pong B0/B1 with depth-1 prefetch, manual 2x unroll (static indices).
//   - ZERO barriers in the 128-iter loop; compiler emits counted vmcnt.
//   - __launch_bounds__(256,2) pins total regs <= 256 -> 2 blocks/CU.
// L2 traffic unchanged vs staged path (slice is XCD-L2-resident); removes
// LDS B-writes, B-reads, and both per-iter barriers.

#define NROW 8192
#define DDIM 512
#define NCLS 100
#define PANEL 64
#define JT 256  // cols per j-tile (4 waves x 64)
#define BK 32

typedef float f32x4 __attribute__((ext_vector_type(4)));
typedef short s16x8 __attribute__((ext_vector_type(8)));

#define GLOBAL_AS __attribute__((address_space(1)))
#define LDS_AS __attribute__((address_space(3)))

__device__ __forceinline__ unsigned short f2bf(float x) {
  unsigned int u = __builtin_bit_cast(unsigned int, x);
  u += 0x7FFFu + ((u >> 16) & 1u);  // round-to-nearest-even
  return (unsigned short)(u >> 16);
}

// One wave per row: L2-norm, scale, cast to bf16. Also zeroes row_pos/row_neg
// (16384 floats over 2048 blocks) — k_row only touches them afterwards.
__global__ void __launch_bounds__(256) k_prep(
    const float* __restrict__ reps, float* __restrict__ row_pos,
    unsigned short* __restrict__ Rb) {
  const int wave = threadIdx.x >> 6;
  const int lane = threadIdx.x & 63;
  const int row = blockIdx.x * 4 + wave;
  if (threadIdx.x < 8) row_pos[blockIdx.x * 8 + threadIdx.x] = 0.0f;
  const float* r = reps + (size_t)row * DDIM;
  float4 v0 = *(const float4*)(r + lane * 4);
  float4 v1 = *(const float4*)(r + 256 + lane * 4);
  float ss = v0.x * v0.x + v0.y * v0.y + v0.z * v0.z + v0.w * v0.w +
             v1.x * v1.x + v1.y * v1.y + v1.z * v1.z + v1.w * v1.w;
#pragma unroll
  for (int m = 1; m < 64; m <<= 1) ss += __shfl_xor(ss, m);
  const float scale = 1.0f / sqrtf(ss);  // norms ~22.6; 1e-8 clamp unreachable
  ushort4 a, b;
  a.x = f2bf(v0.x * scale); a.y = f2bf(v0.y * scale);
  a.z = f2bf(v0.z * scale); a.w = f2bf(v0.w * scale);
  b.x = f2bf(v1.x * scale); b.y = f2bf(v1.y * scale);
  b.z = f2bf(v1.z * scale); b.w = f2bf(v1.w * scale);
  *(ushort4*)(Rb + (size_t)row * DDIM + lane * 4) = a;
  *(ushort4*)(Rb + (size_t)row * DDIM + 256 + lane * 4) = b;
}

// Block = 64-row panel (p = bx>>2) x 2048-col slice (s = bx&3), 4 waves.
// Wave tile per jt: 64 rows x 64 cols = 4a x 4b of 16x16x32 MFMA.
__global__ void __launch_bounds__(256, 2) k_row(
    const unsigned short* __restrict__ Rb, const int* __restrict__ labels,
    float* __restrict__ row_pos, float* __restrict__ row_neg) {
  const int bx = blockIdx.x;
  const int p = bx >> 2;   // row panel 0..127
  const int s = bx & 3;    // j slice 0..3 (fixed per XCD under %8 dispatch)
  const int i0 = p * PANEL;
  const int j0s = s * 2048;

  // A panel only, chunk-major [ch][row][k-in-chunk] (row stride 64B), 64 KB.
  // 2 blocks/CU -> 128 KB LDS. No Bs: B goes L2 -> registers directly.
  __shared__ __attribute__((aligned(16))) unsigned short As[16][PANEL][BK];

  const int tid = threadIdx.x;
  const int lane = tid & 63;
  const int wave = tid >> 6;
  const int quad = lane >> 4, c16 = lane & 15;

  // ---- Stage A panel once, chunk-major: 64 instrs, 16 per wave.
#pragma unroll
  for (int t = 0; t < 16; ++t) {
    const int ii = wave * 16 + t;        // wave-uniform, 0..63
    const int ch = ii >> 2;
    const int rg = (ii & 3) * 16;
    const unsigned short* src =
        Rb + (size_t)(i0 + rg + (lane >> 2)) * DDIM + ch * BK + (lane & 3) * 8;
    __builtin_amdgcn_global_load_lds(
        (GLOBAL_AS void*)const_cast<unsigned short*>(src),
        (LDS_AS void*)(&As[ch][rg][0]), 16, 0, 0);
  }

  // Per-lane row labels and running row sums (live across the whole sweep).
  int li16[16];
  float ps16[16], ns16[16];
#pragma unroll
  for (int a = 0; a < 4; ++a)
#pragma unroll
    for (int r = 0; r < 4; ++r) {
      li16[a * 4 + r] = labels[i0 + a * 16 + quad * 4 + r];
      ps16[a * 4 + r] = 0.0f;
      ns16[a * 4 + r] = 0.0f;
    }

  const float C0 = -5.0f + 1e-7f;  // s = 5g - 5 + 1e-7 (static shift S=10)

  // B fragment byte offsets into Rb for current jt, ch=0. Per-lane contiguous
  // 16 B: row (j0 + wave*64 + b*16 + c16), k-slice quad*8.
  const char* RbB = (const char*)Rb;
  unsigned boff[4];
  s16x8 B0[4], B1[4];
#pragma unroll
  for (int b = 0; b < 4; ++b) {
    boff[b] = (unsigned)(j0s + wave * 64 + b * 16 + c16) * (DDIM * 2) +
              quad * 16;
    B0[b] = *(const s16x8*)(RbB + boff[b]);  // it=0 fragments
  }

  __syncthreads();  // A panel staged (vmcnt(0) drain covers B0 too)

  f32x4 acc[4][4];
  int lj[4], gj[4];

  // One flat iteration: consume Bc (loaded last step), prefetch Bn for it+1.
  // All B indices compile-time (ping-pong via manual 2x unroll) -> registers.
  auto step = [&](s16x8(&Bc)[4], s16x8(&Bn)[4], const int it) {
    const int ch = it & 15;
    if (ch == 0) {
      const int j0 = j0s + (it >> 4) * JT;
#pragma unroll
      for (int b = 0; b < 4; ++b) {
        gj[b] = j0 + wave * 64 + b * 16 + c16;
        lj[b] = labels[gj[b]];
      }
#pragma unroll
      for (int a = 0; a < 4; ++a)
#pragma unroll
        for (int b = 0; b < 4; ++b) acc[a][b] = (f32x4)0.0f;
    }

    // Prefetch next iteration's B fragments (in flight across the MFMAs;
    // compiler emits vmcnt(4) for Bc, keeping these 4 loads outstanding).
    const int itn = it + 1;
    if (itn < 128) {
      if ((itn & 15) == 0) {
#pragma unroll
        for (int b = 0; b < 4; ++b) boff[b] += JT * DDIM * 2;  // next jt
      }
      const int co = (itn & 15) << 6;  // ch*64 bytes
#pragma unroll
      for (int b = 0; b < 4; ++b)
        Bn[b] = *(const s16x8*)(RbB + boff[b] + co);
    }

    // A fragments from LDS (single addr VGPR + immediate offsets).
    s16x8 af[4];
#pragma unroll
    for (int a = 0; a < 4; ++a)
      af[a] = *(const s16x8*)(&As[ch][a * 16 + c16][quad * 8]);

#pragma unroll
    for (int a = 0; a < 4; ++a)
#pragma unroll
      for (int b = 0; b < 4; ++b)
        acc[a][b] = __builtin_amdgcn_mfma_f32_16x16x32_bf16(af[a], Bc[b],
                                                            acc[a][b], 0, 0, 0);

    if (ch == 15) {
#pragma unroll
      for (int a = 0; a < 4; ++a) {
#pragma unroll
        for (int r = 0; r < 4; ++r) {
          const int gi = i0 + a * 16 + quad * 4 + r;
          const int li = li16[a * 4 + r];
          float ps = 0.0f, ns = 0.0f;
#pragma unroll
          for (int b = 0; b < 4; ++b) {
            const float g = acc[a][b][r];
            const float sv = fmaf(g, 5.0f, C0);
            const float ev = __expf(sv);
            const bool same = (li == lj[b]);
            ps += (same && gi != gj[b]) ? sv : 0.0f;
            ns += same ? 0.0f : ev;
          }
          ps16[a * 4 + r] += ps;
          ns16[a * 4 + r] += ns;
        }
      }
    }
  };

#pragma unroll 1
  for (int itp = 0; itp < 64; ++itp) {
    step(B0, B1, itp * 2);
    step(B1, B0, itp * 2 + 1);
  }

  // ---- Block epilogue: reduce per-lane sums -> 64 rows, 2 atomics each.
  // As reused as scratch (all waves past their last As read after the loop).
  __syncthreads();
  float* rp = (float*)As;   // 64 floats
  float* rn = rp + 64;
  if (tid < 128) rp[tid] = 0.0f;
  __syncthreads();
#pragma unroll
  for (int a = 0; a < 4; ++a) {
#pragma unroll
    for (int r = 0; r < 4; ++r) {
      float ps = ps16[a * 4 + r], ns = ns16[a * 4 + r];
#pragma unroll
      for (int m = 1; m < 16; m <<= 1) {  // reduce across the 16 c16 lanes
        ps += __shfl_xor(ps, m);
        ns += __shfl_xor(ns, m);
      }
      if (c16 == 0) {  // 4-way wave contention, once per block: trivial
        atomicAdd(&rp[a * 16 + quad * 4 + r], ps);
        atomicAdd(&rn[a * 16 + quad * 4 + r], ns);
      }
    }
  }
  __syncthreads();
  if (tid < 64) {
    atomicAdd(&row_pos[i0 + tid], rp[tid]);   // 4 adds per address chip-wide
    atomicAdd(&row_neg[i0 + tid], rn[tid]);
  }
}

// LDS label histogram + loss reduction (cnt array eliminated).
__global__ void __launch_bounds__(512) k_final(
    const float* __restrict__ row_pos, const float* __restrict__ row_neg,
    const int* __restrict__ labels, float* __restrict__ out) {
  __shared__ int hcnt[NCLS];
  __shared__ float ssum[8];
  __shared__ float scnt[8];
  const int tid = threadIdx.x;
  if (tid < NCLS) hcnt[tid] = 0;
  __syncthreads();
  for (int i = tid; i < NROW; i += 512) atomicAdd(&hcnt[labels[i]], 1);
  __syncthreads();
  float lsum = 0.0f, lcnt = 0.0f;
  for (int i = tid; i < NROW; i += 512) {
    const float c = (float)(hcnt[labels[i]] - 1);
    const float pos = row_pos[i] / (c + 1e-8f);
    const float loss = -pos + logf(row_neg[i] + 1e-8f);
    if (loss > 0.0f) { lsum += loss; lcnt += 1.0f; }
  }
#pragma unroll
  for (int m = 1; m < 64; m <<= 1) {
    lsum += __shfl_xor(lsum, m);
    lcnt += __shfl_xor(lcnt, m);
  }
  if ((tid & 63) == 0) { ssum[tid >> 6] = lsum; scnt[tid >> 6] = lcnt; }
  __syncthreads();
  if (tid == 0) {
    float S = 0.0f, C = 0.0f;
#pragma unroll
    for (int w = 0; w < 8; ++w) { S += ssum[w]; C += scnt[w]; }
    out[0] = S / (C + 1e-8f);
  }
}

extern "C" void kernel_launch(void* const* d_in, const int* in_sizes, int n_in,
                              void* d_out, int out_size, void* d_ws, size_t ws_size,
                              hipStream_t stream) {
  const float* reps = (const float*)d_in[0];
  const int* labels = (const int*)d_in[1];
  float* out = (float*)d_out;
  char* ws = (char*)d_ws;
  // ws layout: Rb (bf16 normalized reps, 8 MiB) | row_pos | row_neg
  unsigned short* Rb = (unsigned short*)ws;
  float* row_pos = (float*)(ws + (size_t)NROW * DDIM * 2);
  float* row_neg = row_pos + NROW;

  k_prep<<<NROW / 4, 256, 0, stream>>>(reps, row_pos, Rb);
  k_row<<<512, 256, 0, stream>>>(Rb, labels, row_pos, row_neg);
  k_final<<<1, 512, 0, stream>>>(row_pos, row_neg, labels, out);
  (void)in_sizes; (void)n_in; (void)out_size; (void)ws_size;
}

// Round 2
// 183.879 us; speedup vs baseline: 1.0903x; 1.0903x over previous
//
#include <hip/hip_runtime.h>

// SupProtoConLoss on MI355X — round 13: fat wave-tile (64x128), stream A+B.
// League: R7 LDS-B 2-barrier 110.5us; R11 covered-drain 115us; R12 direct-B
// 139us (FAILED: 16 L2 lines/load, depth-1 prefetch -> latency-bound; but
// proved B-side was half the bank conflicts). LDS pipe is the saturated
// resource at 64x64 wave tiles (reads/FLOP = 0.078 B). R13 quadruples the
// FLOPs per LDS byte:
//   - block = 512 thr (8 waves), tile 64 rows x 1024 cols (= full j-slice),
//     wave tile 64x128 -> acc[4][8] (128 AGPR), K streamed in 16 chunks.
//   - slice==block's j-extent => A and B chunks each visited ONCE -> stream
//     both, double-buffered: LDS 2x(4K+64K)=136 KB, 1 block/CU (8 waves/CU,
//     same occupancy as R11's 2x256-thr blocks).
//   - fold/labels once per block (full-K acc) -> loop regs ~200, lb(512,2).
//   - 1 barrier/chunk; stage(ch+1) issued before ds_read+MFMA so the vmcnt
//     drain at the barrier is covered by ~1200cy of compute.
//   - 1024 blocks, slice = bx&7 -> 1 MB B-slice pinned per XCD L2.

#define NROW 8192
#define DDIM 512
#define NCLS 100
#define PANEL 64    // rows per block
#define JCOLS 1024  // cols per block (= slice width)
#define BK 32       // k per chunk
#define NCH 16      // DDIM / BK

typedef float f32x4 __attribute__((ext_vector_type(4)));
typedef short s16x8 __attribute__((ext_vector_type(8)));

#define GLOBAL_AS __attribute__((address_space(1)))
#define LDS_AS __attribute__((address_space(3)))

__device__ __forceinline__ unsigned short f2bf(float x) {
  unsigned int u = __builtin_bit_cast(unsigned int, x);
  u += 0x7FFFu + ((u >> 16) & 1u);  // round-to-nearest-even
  return (unsigned short)(u >> 16);
}

// One wave per row: L2-norm, scale, cast to bf16. Also zeroes row_pos/row_neg
// (16384 floats over 2048 blocks) — k_row only touches them afterwards.
__global__ void __launch_bounds__(256) k_prep(
    const float* __restrict__ reps, float* __restrict__ row_pos,
    unsigned short* __restrict__ Rb) {
  const int wave = threadIdx.x >> 6;
  const int lane = threadIdx.x & 63;
  const int row = blockIdx.x * 4 + wave;
  if (threadIdx.x < 8) row_pos[blockIdx.x * 8 + threadIdx.x] = 0.0f;
  const float* r = reps + (size_t)row * DDIM;
  float4 v0 = *(const float4*)(r + lane * 4);
  float4 v1 = *(const float4*)(r + 256 + lane * 4);
  float ss = v0.x * v0.x + v0.y * v0.y + v0.z * v0.z + v0.w * v0.w +
             v1.x * v1.x + v1.y * v1.y + v1.z * v1.z + v1.w * v1.w;
#pragma unroll
  for (int m = 1; m < 64; m <<= 1) ss += __shfl_xor(ss, m);
  const float scale = 1.0f / sqrtf(ss);  // norms ~22.6; 1e-8 clamp unreachable
  ushort4 a, b;
  a.x = f2bf(v0.x * scale); a.y = f2bf(v0.y * scale);
  a.z = f2bf(v0.z * scale); a.w = f2bf(v0.w * scale);
  b.x = f2bf(v1.x * scale); b.y = f2bf(v1.y * scale);
  b.z = f2bf(v1.z * scale); b.w = f2bf(v1.w * scale);
  *(ushort4*)(Rb + (size_t)row * DDIM + lane * 4) = a;
  *(ushort4*)(Rb + (size_t)row * DDIM + 256 + lane * 4) = b;
}

// Block: 64-row panel (p = bx>>3) x 1024-col slice (s = bx&7), 8 waves.
// Wave tile 64 rows x 128 cols = 4a x 8b of 16x16x32 MFMA, full-K accumulate.
__global__ void __launch_bounds__(512, 2) k_row(
    const unsigned short* __restrict__ Rb, const int* __restrict__ labels,
    float* __restrict__ row_pos, float* __restrict__ row_neg) {
  const int bx = blockIdx.x;
  const int s = bx & 7;   // j slice 0..7 (== XCD under %8 dispatch)
  const int p = bx >> 3;  // row panel 0..127
  const int i0 = p * PANEL;
  const int j0 = s * JCOLS;

  // Double-buffered per-chunk tiles, chunk-major [row][k] (row stride 64 B).
  // 8 KB + 128 KB = 136 KB -> 1 block/CU.
  __shared__ __attribute__((aligned(16))) unsigned short As[2][PANEL][BK];
  __shared__ __attribute__((aligned(16))) unsigned short Bs[2][JCOLS][BK];

  const int tid = threadIdx.x;
  const int lane = tid & 63;
  const int wave = tid >> 6;  // 0..7
  const int quad = lane >> 4, c16 = lane & 15;

  // Stage chunk ch into buffer bb: B = 64 wave-instrs (8/wave), A = 4 (waves
  // 0..3). Sources are 64B-line coalesced; dests linear (gload_lds rule).
  auto stage = [&](int ch, int bb) {
#pragma unroll
    for (int t = 0; t < 8; ++t) {
      const int ob = (wave * 8 + t) * 64;  // wave-uniform 16B-unit base
      const int sl = ob + lane;            // col = sl>>2, koct = sl&3
      const unsigned short* src =
          Rb + (size_t)(j0 + (sl >> 2)) * DDIM + ch * BK + (sl & 3) * 8;
      __builtin_amdgcn_global_load_lds(
          (GLOBAL_AS void*)const_cast<unsigned short*>(src),
          (LDS_AS void*)(&Bs[bb][0][0] + (size_t)ob * 8), 16, 0, 0);
    }
    if (wave < 4) {
      const int oa = wave * 64;
      const int sl = oa + lane;
      const unsigned short* src =
          Rb + (size_t)(i0 + (sl >> 2)) * DDIM + ch * BK + (sl & 3) * 8;
      __builtin_amdgcn_global_load_lds(
          (GLOBAL_AS void*)const_cast<unsigned short*>(src),
          (LDS_AS void*)(&As[bb][0][0] + (size_t)oa * 8), 16, 0, 0);
    }
  };

  const float C0 = -5.0f + 1e-7f;  // s = 5g - 5 + 1e-7 (static shift S=10)

  f32x4 acc[4][8];
#pragma unroll
  for (int a = 0; a < 4; ++a)
#pragma unroll
    for (int b = 0; b < 8; ++b) acc[a][b] = (f32x4)0.0f;

  stage(0, 0);
  __syncthreads();  // chunk 0 staged (compiler drains vmcnt before barrier)

#pragma unroll 2
  for (int ch = 0; ch < NCH; ++ch) {
    const int cur = ch & 1;
    if (ch + 1 < NCH) stage(ch + 1, cur ^ 1);  // in flight across the MFMAs

    s16x8 af[4], bf8[8];
#pragma unroll
    for (int a = 0; a < 4; ++a)
      af[a] = *(const s16x8*)(&As[cur][a * 16 + c16][quad * 8]);
#pragma unroll
    for (int b = 0; b < 8; ++b)
      bf8[b] = *(const s16x8*)(&Bs[cur][wave * 128 + b * 16 + c16][quad * 8]);

#pragma unroll
    for (int a = 0; a < 4; ++a)
#pragma unroll
      for (int b = 0; b < 8; ++b)
        acc[a][b] = __builtin_amdgcn_mfma_f32_16x16x32_bf16(af[a], bf8[b],
                                                            acc[a][b], 0, 0, 0);

    __syncthreads();  // stage(ch+1) drained (covered) + buffer-swap safety
  }

  // ---- Epilogue (once per block: acc holds full-K gram tile).
  // As[0] reused as scratch: last read of As was the loop's final barrier.
  float* rp = (float*)&As[0][0][0];  // 64 floats
  float* rn = rp + 64;
  if (tid < 128) rp[tid] = 0.0f;
  __syncthreads();

  int lj[8], gjc[8];
#pragma unroll
  for (int b = 0; b < 8; ++b) {
    gjc[b] = j0 + wave * 128 + b * 16 + c16;
    lj[b] = labels[gjc[b]];
  }

#pragma unroll
  for (int a = 0; a < 4; ++a) {
#pragma unroll
    for (int r = 0; r < 4; ++r) {
      const int gi = i0 + a * 16 + quad * 4 + r;
      const int li = labels[gi];
      float ps = 0.0f, ns = 0.0f;
#pragma unroll
      for (int b = 0; b < 8; ++b) {
        const float g = acc[a][b][r];
        const float sv = fmaf(g, 5.0f, C0);
        const float ev = __expf(sv);
        const bool same = (li == lj[b]);
        ps += (same && gi != gjc[b]) ? sv : 0.0f;
        ns += same ? 0.0f : ev;
      }
#pragma unroll
      for (int m = 1; m < 16; m <<= 1) {  // reduce across the 16 c16 lanes
        ps += __shfl_xor(ps, m);
        ns += __shfl_xor(ns, m);
      }
      if (c16 == 0) {  // 8 waves x 4 quads contend lightly, once per block
        atomicAdd(&rp[a * 16 + quad * 4 + r], ps);
        atomicAdd(&rn[a * 16 + quad * 4 + r], ns);
      }
    }
  }
  __syncthreads();
  if (tid < 64) {
    atomicAdd(&row_pos[i0 + tid], rp[tid]);  // 8 adds per address chip-wide
    atomicAdd(&row_neg[i0 + tid], rn[tid]);
  }
}

// LDS label histogram + loss reduction (cnt array eliminated).
__global__ void __launch_bounds__(512) k_final(
    const float* __restrict__ row_pos, const float* __restrict__ row_neg,
    const int* __restrict__ labels, float* __restrict__ out) {
  __shared__ int hcnt[NCLS];
  __shared__ float ssum[8];
  __shared__ float scnt[8];
  const int tid = threadIdx.x;
  if (tid < NCLS) hcnt[tid] = 0;
  __syncthreads();
  for (int i = tid; i < NROW; i += 512) atomicAdd(&hcnt[labels[i]], 1);
  __syncthreads();
  float lsum = 0.0f, lcnt = 0.0f;
  for (int i = tid; i < NROW; i += 512) {
    const float c = (float)(hcnt[labels[i]] - 1);
    const float pos = row_pos[i] / (c + 1e-8f);
    const float loss = -pos + logf(row_neg[i] + 1e-8f);
    if (loss > 0.0f) { lsum += loss; lcnt += 1.0f; }
  }
#pragma unroll
  for (int m = 1; m < 64; m <<= 1) {
    lsum += __shfl_xor(lsum, m);
    lcnt += __shfl_xor(lcnt, m);
  }
  if ((tid & 63) == 0) { ssum[tid >> 6] = lsum; scnt[tid >> 6] = lcnt; }
  __syncthreads();
  if (tid == 0) {
    float S = 0.0f, C = 0.0f;
#pragma unroll
    for (int w = 0; w < 8; ++w) { S += ssum[w]; C += scnt[w]; }
    out[0] = S / (C + 1e-8f);
  }
}

extern "C" void kernel_launch(void* const* d_in, const int* in_sizes, int n_in,
                              void* d_out, int out_size, void* d_ws, size_t ws_size,
                              hipStream_t stream) {
  const float* reps = (const float*)d_in[0];
  const int* labels = (const int*)d_in[1];
  float* out = (float*)d_out;
  char* ws = (char*)d_ws;
  // ws layout: Rb (bf16 normalized reps, 8 MiB) | row_pos | row_neg
  unsigned short* Rb = (unsigned short*)ws;
  float* row_pos = (float*)(ws + (size_t)NROW * DDIM * 2);
  float* row_neg = row_pos + NROW;

  k_prep<<<NROW / 4, 256, 0, stream>>>(reps, row_pos, Rb);
  k_row<<<NROW / PANEL * 8, 512, 0, stream>>>(Rb, labels, row_pos, row_neg);
  k_final<<<1, 512, 0, stream>>>(row_pos, row_neg, labels, out);
  (void)in_sizes; (void)n_in; (void)out_size; (void)ws_size;
}

// Round 3
// 169.012 us; speedup vs baseline: 1.1862x; 1.0880x over previous
//
#include <hip/hip_runtime.h>

// SupProtoConLoss on MI355X — round 14: 8-phase counted-vmcnt 256^2 GEMM.
// League: R7 2-barrier 110.5us (622 TF); R11 115; R13 fat-tile 124 (554 TF).
// All 2-phase variants sit in the documented 2-phase band (~600-680 TF);
// T2 swizzle / T5 setprio are null there. R14 ports the verified 8-phase
// template (m201): 256x256 tile, BK=64, 4 phases/K-step x 16 MFMA, one
// half-tile staged per phase, ONE vmcnt(4) per K-step placed before the
// K-step's final s_barrier (vmcnt->barrier = cross-wave DMA fence), raw
// barriers elsewhere (no vmcnt(0) drain in the loop), st-swizzled LDS via
// pre-permuted global source + same-XOR ds_read, setprio around MFMA,
// fold/epilogue once per block. LDS 128KB -> 1 block/CU (8 waves).

#define NROW 8192
#define DDIM 512
#define NCLS 100
#define BKS 64    // k per K-step
#define KSTEPS 8  // DDIM / BKS

typedef float f32x4 __attribute__((ext_vector_type(4)));
typedef short s16x8 __attribute__((ext_vector_type(8)));

#define GLOBAL_AS __attribute__((address_space(1)))
#define LDS_AS __attribute__((address_space(3)))

__device__ __forceinline__ unsigned short f2bf(float x) {
  unsigned int u = __builtin_bit_cast(unsigned int, x);
  u += 0x7FFFu + ((u >> 16) & 1u);  // round-to-nearest-even
  return (unsigned short)(u >> 16);
}

// One wave per row: L2-norm, scale, cast to bf16. Also zeroes row_pos/row_neg
// (16384 floats over 2048 blocks) — k_row only touches them afterwards.
__global__ void __launch_bounds__(256) k_prep(
    const float* __restrict__ reps, float* __restrict__ row_pos,
    unsigned short* __restrict__ Rb) {
  const int wave = threadIdx.x >> 6;
  const int lane = threadIdx.x & 63;
  const int row = blockIdx.x * 4 + wave;
  if (threadIdx.x < 8) row_pos[blockIdx.x * 8 + threadIdx.x] = 0.0f;
  const float* r = reps + (size_t)row * DDIM;
  float4 v0 = *(const float4*)(r + lane * 4);
  float4 v1 = *(const float4*)(r + 256 + lane * 4);
  float ss = v0.x * v0.x + v0.y * v0.y + v0.z * v0.z + v0.w * v0.w +
             v1.x * v1.x + v1.y * v1.y + v1.z * v1.z + v1.w * v1.w;
#pragma unroll
  for (int m = 1; m < 64; m <<= 1) ss += __shfl_xor(ss, m);
  const float scale = 1.0f / sqrtf(ss);  // norms ~22.6; 1e-8 clamp unreachable
  ushort4 a, b;
  a.x = f2bf(v0.x * scale); a.y = f2bf(v0.y * scale);
  a.z = f2bf(v0.z * scale); a.w = f2bf(v0.w * scale);
  b.x = f2bf(v1.x * scale); b.y = f2bf(v1.y * scale);
  b.z = f2bf(v1.z * scale); b.w = f2bf(v1.w * scale);
  *(ushort4*)(Rb + (size_t)row * DDIM + lane * 4) = a;
  *(ushort4*)(Rb + (size_t)row * DDIM + 256 + lane * 4) = b;
}

// Block: 256x256 output tile, 8 waves as 2(M) x 4(N); wave tile 128x64 =
// acc[8][4] of 16x16x32. LDS shorts: A(buf b) at b*16384, B at 32768+b*16384.
// Half-tile = 128 rows x 64 k = 8192 shorts. Swizzle: 16B slot l of row r
// lives at physical slot l^(r&7) (both staged and read with the same XOR).
__global__ void __launch_bounds__(512, 2) k_row(
    const unsigned short* __restrict__ Rb, const int* __restrict__ labels,
    float* __restrict__ row_pos, float* __restrict__ row_neg) {
  const int bx = blockIdx.x;
  const int idx = bx >> 3;                 // 0..127
  const int tn = (bx & 7) * 4 + (idx >> 5);  // XCD-pinned j supercolumn
  const int tm = idx & 31;
  const int i0 = tm * 256;
  const int j0 = tn * 256;

  __shared__ __attribute__((aligned(16))) unsigned short LDSH[65536];  // 128KB

  const int tid = threadIdx.x;
  const int lane = tid & 63;
  const int wave = tid >> 6;  // 0..7
  const int wr = wave >> 2, wc = wave & 3;
  const int quad = lane >> 4, c16 = lane & 15;

  // ---- staging: per-lane source permutation (involution of read-side XOR)
  const int srow = lane >> 3;                    // row-within-8 for this lane
  const int skoff = ((lane & 7) ^ srow) * 8;     // permuted 16B slot (shorts)

  // h: 0=A0,1=A1,2=B0,3=B1. kt2 = target K-step (pre-masked). 2 loads/wave.
  auto stageHalf = [&](int h, int kt2) {
    const int bb = kt2 & 1;
    const int base =
        (h < 2 ? 0 : 32768) + bb * 16384 + (h & 1) * 8192 + wave * 1024;
    const int r0 = (h < 2 ? i0 : j0) + (h & 1) * 128;
#pragma unroll
    for (int t = 0; t < 2; ++t) {
      const unsigned short* src = Rb +
          (size_t)(r0 + wave * 16 + t * 8 + srow) * DDIM + kt2 * BKS + skoff;
      __builtin_amdgcn_global_load_lds(
          (GLOBAL_AS void*)const_cast<unsigned short*>(src),
          (LDS_AS void*)(LDSH + base + t * 512), 16, 0, 0);
    }
  };

  // ---- ds_read bases (shorts). Row stride 64 shorts; swizzled slot term.
  const int x7 = c16 & 7;
  const int sp0 = ((0 * 4 + quad) ^ x7) * 8;  // ksub 0
  const int sp1 = ((1 * 4 + quad) ^ x7) * 8;  // ksub 1
  auto LD = [&](int si) { return *(const s16x8*)(LDSH + si); };

  f32x4 acc[8][4];
#pragma unroll
  for (int m = 0; m < 8; ++m)
#pragma unroll
    for (int n = 0; n < 4; ++n) acc[m][n] = (f32x4)0.0f;

  // ---- prologue: A(0),B(0) -> buf0; B(1) -> buf1. 12 loads/wave.
  stageHalf(0, 0); stageHalf(1, 0); stageHalf(2, 0); stageHalf(3, 0);
  stageHalf(2, 1); stageHalf(3, 1);
  asm volatile("s_waitcnt vmcnt(4)" ::: "memory");  // A(0)+B(0) done, B(1) fly
  __builtin_amdgcn_s_barrier();

#pragma unroll 1
  for (int kt = 0; kt < KSTEPS; ++kt) {
    const int cb = (kt & 1) * 16384;
    const int aK0 = cb + wr * 8192 + c16 * 64 + sp0;
    const int aK1 = cb + wr * 8192 + c16 * 64 + sp1;
    const int bK0 = 32768 + cb + wc * 4096 + c16 * 64 + sp0;
    const int bK1 = 32768 + cb + wc * 4096 + c16 * 64 + sp1;
    const int ktn1 = (kt + 1) & 7, ktn2 = (kt + 2) & 7;
    s16x8 aH[4][2], bF[4][2];

    // ---- phase 0: read A[mh0]+B[nh0], stage A0(kt+1), MFMA Q(0,0)
#pragma unroll
    for (int m = 0; m < 4; ++m) {
      aH[m][0] = LD(aK0 + m * 1024);
      aH[m][1] = LD(aK1 + m * 1024);
    }
#pragma unroll
    for (int n = 0; n < 2; ++n) {
      bF[n][0] = LD(bK0 + n * 1024);
      bF[n][1] = LD(bK1 + n * 1024);
    }
    stageHalf(0, ktn1);
    __builtin_amdgcn_sched_barrier(0);
    __builtin_amdgcn_s_barrier();
    __builtin_amdgcn_s_setprio(1);
#pragma unroll
    for (int m = 0; m < 4; ++m)
#pragma unroll
      for (int n = 0; n < 2; ++n) {
        acc[m][n] = __builtin_amdgcn_mfma_f32_16x16x32_bf16(aH[m][0], bF[n][0],
                                                            acc[m][n], 0, 0, 0);
        acc[m][n] = __builtin_amdgcn_mfma_f32_16x16x32_bf16(aH[m][1], bF[n][1],
                                                            acc[m][n], 0, 0, 0);
      }
    __builtin_amdgcn_s_setprio(0);
    __builtin_amdgcn_sched_barrier(0);
    __builtin_amdgcn_s_barrier();

    // ---- phase 1: read B[nh1], stage A1(kt+1), MFMA Q(0,1)
#pragma unroll
    for (int n = 2; n < 4; ++n) {
      bF[n][0] = LD(bK0 + n * 1024);
      bF[n][1] = LD(bK1 + n * 1024);
    }
    stageHalf(1, ktn1);
    __builtin_amdgcn_sched_barrier(0);
    __builtin_amdgcn_s_barrier();
    __builtin_amdgcn_s_setprio(1);
#pragma unroll
    for (int m = 0; m < 4; ++m)
#pragma unroll
      for (int n = 2; n < 4; ++n) {
        acc[m][n] = __builtin_amdgcn_mfma_f32_16x16x32_bf16(aH[m][0], bF[n][0],
                                                            acc[m][n], 0, 0, 0);
        acc[m][n] = __builtin_amdgcn_mfma_f32_16x16x32_bf16(aH[m][1], bF[n][1],
                                                            acc[m][n], 0, 0, 0);
      }
    __builtin_amdgcn_s_setprio(0);
    __builtin_amdgcn_sched_barrier(0);
    __builtin_amdgcn_s_barrier();

    // ---- phase 2: read A[mh1], stage B0(kt+2), MFMA Q(1,0)
#pragma unroll
    for (int m = 0; m < 4; ++m) {
      aH[m][0] = LD(aK0 + (m + 4) * 1024);
      aH[m][1] = LD(aK1 + (m + 4) * 1024);
    }
    stageHalf(2, ktn2);
    __builtin_amdgcn_sched_barrier(0);
    __builtin_amdgcn_s_barrier();
    __builtin_amdgcn_s_setprio(1);
#pragma unroll
    for (int m = 0; m < 4; ++m)
#pragma unroll
      for (int n = 0; n < 2; ++n) {
        acc[m + 4][n] = __builtin_amdgcn_mfma_f32_16x16x32_bf16(
            aH[m][0], bF[n][0], acc[m + 4][n], 0, 0, 0);
        acc[m + 4][n] = __builtin_amdgcn_mfma_f32_16x16x32_bf16(
            aH[m][1], bF[n][1], acc[m + 4][n], 0, 0, 0);
      }
    __builtin_amdgcn_s_setprio(0);
    __builtin_amdgcn_sched_barrier(0);
    __builtin_amdgcn_s_barrier();

    // ---- phase 3: stage B1(kt+2), MFMA Q(1,1), then the K-step fence:
    // vmcnt(4) BEFORE the barrier => all waves' A(kt+1)/B(kt+1) DMAs landed.
    stageHalf(3, ktn2);
    __builtin_amdgcn_sched_barrier(0);
    __builtin_amdgcn_s_barrier();
    __builtin_amdgcn_s_setprio(1);
#pragma unroll
    for (int m = 0; m < 4; ++m)
#pragma unroll
      for (int n = 2; n < 4; ++n) {
        acc[m + 4][n] = __builtin_amdgcn_mfma_f32_16x16x32_bf16(
            aH[m][0], bF[n][0], acc[m + 4][n], 0, 0, 0);
        acc[m + 4][n] = __builtin_amdgcn_mfma_f32_16x16x32_bf16(
            aH[m][1], bF[n][1], acc[m + 4][n], 0, 0, 0);
      }
    __builtin_amdgcn_s_setprio(0);
    __builtin_amdgcn_sched_barrier(0);
    asm volatile("s_waitcnt vmcnt(4)" ::: "memory");
    __builtin_amdgcn_s_barrier();
  }

  // ---- epilogue: fold + row reduction, once per block.
  __syncthreads();  // drains remaining DMAs -> LDS reusable
  float* rp = (float*)&LDSH[0];  // 256 floats
  float* rn = rp + 256;
  ((float*)&LDSH[0])[tid] = 0.0f;  // tid<512 zeroes rp+rn exactly
  __syncthreads();

  const float C0 = -5.0f + 1e-7f;  // s = 5g - 5 + 1e-7 (static shift S=10)
  int lj[4], gj4[4];
#pragma unroll
  for (int n = 0; n < 4; ++n) {
    gj4[n] = j0 + wc * 64 + n * 16 + c16;
    lj[n] = labels[gj4[n]];
  }
#pragma unroll
  for (int m = 0; m < 8; ++m) {
#pragma unroll
    for (int r = 0; r < 4; ++r) {
      const int lrow = wr * 128 + m * 16 + quad * 4 + r;
      const int gi = i0 + lrow;
      const int li = labels[gi];
      float ps = 0.0f, ns = 0.0f;
#pragma unroll
      for (int n = 0; n < 4; ++n) {
        const float g = acc[m][n][r];
        const float sv = fmaf(g, 5.0f, C0);
        const float ev = __expf(sv);
        const bool same = (li == lj[n]);
        ps += (same && gi != gj4[n]) ? sv : 0.0f;
        ns += same ? 0.0f : ev;
      }
#pragma unroll
      for (int mm = 1; mm < 16; mm <<= 1) {  // reduce across the 16 c16 lanes
        ps += __shfl_xor(ps, mm);
        ns += __shfl_xor(ns, mm);
      }
      if (c16 == 0) {  // 4 wc-waves contend per address, once per block
        atomicAdd(&rp[lrow], ps);
        atomicAdd(&rn[lrow], ns);
      }
    }
  }
  __syncthreads();
  if (tid < 256) {
    atomicAdd(&row_pos[i0 + tid], rp[tid]);  // 32 adds per address chip-wide
    atomicAdd(&row_neg[i0 + tid], rn[tid]);
  }
}

// LDS label histogram + loss reduction (cnt array eliminated).
__global__ void __launch_bounds__(512) k_final(
    const float* __restrict__ row_pos, const float* __restrict__ row_neg,
    const int* __restrict__ labels, float* __restrict__ out) {
  __shared__ int hcnt[NCLS];
  __shared__ float ssum[8];
  __shared__ float scnt[8];
  const int tid = threadIdx.x;
  if (tid < NCLS) hcnt[tid] = 0;
  __syncthreads();
  for (int i = tid; i < NROW; i += 512) atomicAdd(&hcnt[labels[i]], 1);
  __syncthreads();
  float lsum = 0.0f, lcnt = 0.0f;
  for (int i = tid; i < NROW; i += 512) {
    const float c = (float)(hcnt[labels[i]] - 1);
    const float pos = row_pos[i] / (c + 1e-8f);
    const float loss = -pos + logf(row_neg[i] + 1e-8f);
    if (loss > 0.0f) { lsum += loss; lcnt += 1.0f; }
  }
#pragma unroll
  for (int m = 1; m < 64; m <<= 1) {
    lsum += __shfl_xor(lsum, m);
    lcnt += __shfl_xor(lcnt, m);
  }
  if ((tid & 63) == 0) { ssum[tid >> 6] = lsum; scnt[tid >> 6] = lcnt; }
  __syncthreads();
  if (tid == 0) {
    float S = 0.0f, C = 0.0f;
#pragma unroll
    for (int w = 0; w < 8; ++w) { S += ssum[w]; C += scnt[w]; }
    out[0] = S / (C + 1e-8f);
  }
}

extern "C" void kernel_launch(void* const* d_in, const int* in_sizes, int n_in,
                              void* d_out, int out_size, void* d_ws, size_t ws_size,
                              hipStream_t stream) {
  const float* reps = (const float*)d_in[0];
  const int* labels = (const int*)d_in[1];
  float* out = (float*)d_out;
  char* ws = (char*)d_ws;
  // ws layout: Rb (bf16 normalized reps, 8 MiB) | row_pos | row_neg
  unsigned short* Rb = (unsigned short*)ws;
  float* row_pos = (float*)(ws + (size_t)NROW * DDIM * 2);
  float* row_neg = row_pos + NROW;

  k_prep<<<NROW / 4, 256, 0, stream>>>(reps, row_pos, Rb);
  k_row<<<1024, 512, 0, stream>>>(Rb, labels, row_pos, row_neg);
  k_final<<<1, 512, 0, stream>>>(row_pos, row_neg, labels, out);
  (void)in_sizes; (void)n_in; (void)out_size; (void)ws_size;
}